// Round 14
// baseline (130.477 us; speedup 1.0000x reference)
//
#include <hip/hip_runtime.h>

#define NQ   12
#define DIM  4096
#define NL   4
#define BLK  64

typedef unsigned short u16;
typedef unsigned int   u32;
typedef unsigned long long u64;
typedef float f2 __attribute__((ext_vector_type(2)));

static constexpr int par(u32 v){ return __builtin_popcount(v)&1; }

// ---------- compile-time GF(2) linear algebra for the CNOT-chain permutation ----------
struct L12 { u16 b[NQ]; };

static constexpr u32 lap(const L12& A, u32 x){ u32 r=0; for(int p=0;p<NQ;++p) if((x>>p)&1u) r^=A.b[p]; return r; }
static constexpr L12 lcomp(const L12& A, const L12& B){ L12 r{}; for(int p=0;p<NQ;++p) r.b[p]=(u16)lap(A,(u32)B.b[p]); return r; }
static constexpr L12 lident(){ L12 r{}; for(int p=0;p<NQ;++p) r.b[p]=(u16)(1u<<p); return r; }

static constexpr u32 applyT(u32 i){
  i ^= ((i>>0)&1u) << 11;                            // CNOT(11,0): bit11 ^= bit0
  for(int q=10;q>=0;--q){ int pc2=11-q, pt=10-q; i ^= ((i>>pc2)&1u) << pt; }
  return i;
}
static constexpr L12 lT(){ L12 t{}; for(int p=0;p<NQ;++p) t.b[p]=(u16)applyT(1u<<p); return t; }

static constexpr L12 linv(const L12& A){              // GF(2) Gauss-Jordan
  u16 v[NQ]={}; u16 u[NQ]={};
  for(int p=0;p<NQ;++p){ v[p]=A.b[p]; u[p]=(u16)(1u<<p); }
  for(int t=0;t<NQ;++t){
    int p=t; while(!((v[p]>>t)&1u)) ++p;
    u16 tv=v[p]; v[p]=v[t]; v[t]=tv; u16 tu=u[p]; u[p]=u[t]; u[t]=tu;
    for(int k=0;k<NQ;++k) if(k!=t && ((v[k]>>t)&1u)){ v[k]^=v[t]; u[k]^=u[t]; }
  }
  L12 r{}; for(int p=0;p<NQ;++p) r.b[p]=u[p]; return r;
}
static constexpr L12 ltr(const L12& A){
  L12 r{}; for(int p=0;p<NQ;++p) for(int q=0;q<NQ;++q) if((A.b[p]>>q)&1u) r.b[q]=(u16)(r.b[q]|(1u<<p));
  return r;
}

struct Tables {
  u16 A[NL][12];   // A_l: stored-index mask of true-qubit position p at layer l
  u16 W[NL][12];   // W_l = A_l^{-T}: role functionals
  u16 wexp[12];    // final readout parity masks
};

static constexpr Tables make_tables(){
  Tables tb{};
  const L12 T   = lT();
  const L12 Tit = ltr(linv(T));
  L12 A = lident();
  L12 W = lident();
  for(int l=0;l<NL;++l){
    for(int p=0;p<12;++p){ tb.A[l][p]=A.b[p]; tb.W[l][p]=W.b[p]; }
    A = lcomp(A, T);
    W = lcomp(W, Tit);
  }
  for(int p=0;p<12;++p) tb.wexp[p]=W.b[p];
  return tb;
}

// ---------- LDS swizzle: slot = j ^ fold(j>>4), fold linear over GF(2) ----------
static constexpr u16 UIMG[12] = {1,2,4,8, 3,5,6,7, 9,10,11,13};
static constexpr u32 swz(u32 j){
  u32 f=0;
  for(int k=4;k<12;++k) if((j>>k)&1u) f ^= (u32)UIMG[k];
  return j ^ (f & 15u);
}

// ---------- trip tables: 8 trips x 6 gates (layer l = t/2, positions 6*(t&1)..+5) ----------
struct Trip6 {
  u32 lane_c[6];   // tid bit k -> swz(1<<pos)<<3 | role-bits(6)<<26
  u32 raw6[6];     // 1<<pos
  u32 smb[6];      // swz(M_k)<<3
  u32 rawm[6];     // M_k
  u32 scmb[64];    // swz(combo)<<3
  u32 cinv[6];     // rows of C^{-1} (C[i][k] = <M_k, w_i>) when cok
  u64 rho[6];      // residual role bit per combo c (excludes k=i term)
  bool cok;
};

static constexpr Trip6 make_trip(int t){
  Trip6 r{};
  const Tables tb = make_tables();
  const int l = t>>1, h = (t&1)*6;
  u16 M[6]={}, w[6]={};
  for(int j=0;j<6;++j){ M[j]=tb.A[l][h+j]; w[j]=tb.W[l][h+j]; }
  // free positions = non-pivots of span{M} (rank 6 -> exactly 6 free)
  u16 ech[12]={};
  for(int j=0;j<6;++j){
    u16 x=M[j];
    while(x){
      int lb=11; while(!((x>>lb)&1)) --lb;
      if(ech[lb]) x=(u16)(x^ech[lb]); else { ech[lb]=x; break; }
    }
  }
  int np[12]={}; int nn=0;
  for(int p=0;p<12;++p) if(!ech[p]) np[nn++]=p;
  // order: first 4 lane bits get fold-images of rank 4 (16-lane phase spread)
  int ord[6]={0,1,2,3,4,5};
  {
    int bi=-1;
    for(int ms=0; ms<64 && bi<0; ++ms){
      if(__builtin_popcount((unsigned)ms)!=4) continue;
      u16 bas[4]={0,0,0,0}; int rk=0;
      for(int k=0;k<6;++k){
        if(!((ms>>k)&1)) continue;
        u16 x=(u16)(swz(1u<<np[k])&15u);
        while(x){
          int hb2=3; while(hb2>0&&!((x>>hb2)&1))--hb2;
          if(bas[hb2]) x=(u16)(x^bas[hb2]); else { bas[hb2]=x; ++rk; x=0; }
        }
      }
      if(rk==4) bi=ms;
    }
    if(bi>=0){
      int tmp[6]={}; int lo=0, hi=4;
      for(int k=0;k<6;++k){ if((bi>>k)&1) tmp[lo++]=k; else tmp[hi++]=k; }
      for(int k=0;k<6;++k) ord[k]=tmp[k];
    }
  }
  for(int k=0;k<6;++k){
    const int pos=np[ord[k]];
    u32 nib=0;
    for(int i=0;i<6;++i) nib |= (u32)((w[i]>>pos)&1u)<<i;
    r.lane_c[k] = (swz(1u<<pos)<<3)|(nib<<26);
    r.raw6[k]=1u<<pos;
  }
  for(int i=0;i<6;++i){ r.smb[i]=swz((u32)M[i])<<3; r.rawm[i]=(u32)M[i]; }
  for(int c=0;c<64;++c){
    u32 m=0;
    for(int j=0;j<6;++j) if((c>>j)&1) m^=(u32)M[j];
    r.scmb[c]=swz(m)<<3;
  }
  // C[i][k] = <M_k, w_i>; invert [C|I]
  u32 Cm[6]={};
  for(int i=0;i<6;++i){ u32 row=0; for(int k=0;k<6;++k) row|=(u32)par((u32)(M[k]&w[i]))<<k; Cm[i]=row; }
  u32 rows[6]={};
  for(int i=0;i<6;++i) rows[i]=Cm[i]|(1u<<(6+i));
  bool ok=true;
  for(int col=0;col<6;++col){
    int pv=-1;
    for(int rr=col;rr<6;++rr) if((rows[rr]>>col)&1u){pv=rr;break;}
    if(pv<0){ok=false;break;}
    u32 tt=rows[col]; rows[col]=rows[pv]; rows[pv]=tt;
    for(int rr=0;rr<6;++rr) if(rr!=col && ((rows[rr]>>col)&1u)) rows[rr]^=rows[col];
  }
  r.cok=ok;
  if(ok) for(int k=0;k<6;++k) r.cinv[k]=(rows[k]>>6)&63u;
  for(int i=0;i<6;++i){
    u64 m=0;
    for(int c=0;c<64;++c){
      int v=0;
      for(int k=0;k<6;++k) if(k!=i && ((c>>k)&1)) v ^= (int)((Cm[i]>>k)&1u);
      m |= (u64)v<<c;
    }
    r.rho[i]=m;
  }
  return r;
}

static constexpr Trip6 TR0 = make_trip(0);
static constexpr Trip6 TR1 = make_trip(1);
static constexpr Trip6 TR2 = make_trip(2);
static constexpr Trip6 TR3 = make_trip(3);
static constexpr Trip6 TR4 = make_trip(4);
static constexpr Trip6 TR5 = make_trip(5);
static constexpr Trip6 TR6 = make_trip(6);
static constexpr Trip6 TR7 = make_trip(7);
__device__ constexpr Trip6 TRIPS[8] = {TR0,TR1,TR2,TR3,TR4,TR5,TR6,TR7};

// ---------- readout tables (trip 7 = layer 3, positions 6..11) ----------
struct RD { u16 pm[12]; u16 mu[12]; };
static constexpr RD make_rd(){
  RD r{};
  const Tables tb=make_tables();
  for(int q=0;q<12;++q){
    r.pm[q]=tb.wexp[11-q];
    u32 m=0;
    for(int j=0;j<6;++j) m|=(u32)par((u32)(tb.A[3][6+j]&tb.wexp[11-q]))<<j;
    r.mu[q]=(u16)m;
  }
  return r;
}
__device__ constexpr RD RDT = make_rd();

__device__ __forceinline__ float fx(float a, u32 m){ return __uint_as_float(__float_as_uint(a)^m); }

// ---------- one gate (G = TI*6+J, combo bit J); 3-shear RY + 3-shear RZ ----------
// gw[G] = {tan(ty/4), sin(ty/2), tan(tz/2), sin(tz)}; gwH[G] = {tan(tz/4), sin(tz/2),-,-}
template<int TI, int J>
__device__ __forceinline__ void one_gate(f2 (&a)[64], const float4* __restrict__ gw,
                                         const float4* __restrict__ gwH, u32 nib){
  constexpr int G = TI*6+J;
  constexpr bool WITHW = (TI < 6);          // layer 3: RZ dropped (|amp|^2 readout)
  const float4 g = gw[G];
  if constexpr (TRIPS[TI].cok){
#pragma unroll
    for(int c=0;c<64;++c){
      if((c>>J)&1) continue;
      const int c1=c|(1<<J);
      const bool sw = (TRIPS[TI].rho[J]>>c)&1ull;
      const int p = sw?c1:c, q = sw?c:c1;
      f2 u,v;
      u.x=fmaf(-g.x,a[q].x,a[p].x); u.y=fmaf(-g.x,a[q].y,a[p].y);
      v.x=fmaf( g.y,u.x,a[q].x);    v.y=fmaf( g.y,u.y,a[q].y);
      a[p].x=fmaf(-g.x,v.x,u.x);    a[p].y=fmaf(-g.x,v.y,u.y);
      if(WITHW){ const float t=fmaf(-g.z,v.y,v.x); v.y=fmaf(g.w,t,v.y); v.x=fmaf(-g.z,v.y,t); }
      a[q]=v;
    }
  } else {
    // runtime role path: sign-xored constants + two-sided half-angle RZ
    const u32 Rm = ((nib>>J)&1u)<<31;
    const float tg=fx(g.x,Rm), sg=fx(g.y,Rm);
    float t2=0.f, s2=0.f;
    if constexpr (WITHW){
      const float4 hh=gwH[G];
      t2=fx(hh.x,Rm^0x80000000u); s2=fx(hh.y,Rm^0x80000000u);
    }
#pragma unroll
    for(int c=0;c<64;++c){
      if((c>>J)&1) continue;
      const int c1=c|(1<<J);
      if(((TRIPS[TI].rho[J]>>c)&1ull)==0){
        f2 u,v;
        u.x=fmaf(-tg,a[c1].x,a[c].x); u.y=fmaf(-tg,a[c1].y,a[c].y);
        v.x=fmaf( sg,u.x,a[c1].x);    v.y=fmaf( sg,u.y,a[c1].y);
        a[c].x=fmaf(-tg,v.x,u.x);     a[c].y=fmaf(-tg,v.y,u.y);
        a[c1]=v;
        if(WITHW){
          float tt=fmaf(-t2,a[c].y,a[c].x);   a[c].y=fmaf( s2,tt,a[c].y);   a[c].x=fmaf(-t2,a[c].y,tt);
          tt=fmaf( t2,a[c1].y,a[c1].x);       a[c1].y=fmaf(-s2,tt,a[c1].y); a[c1].x=fmaf( t2,a[c1].y,tt);
        }
      } else {
        f2 u,v;
        u.x=fmaf( tg,a[c1].x,a[c].x); u.y=fmaf( tg,a[c1].y,a[c].y);
        v.x=fmaf(-sg,u.x,a[c1].x);    v.y=fmaf(-sg,u.y,a[c1].y);
        a[c].x=fmaf( tg,v.x,u.x);     a[c].y=fmaf( tg,v.y,u.y);
        a[c1]=v;
        if(WITHW){
          float tt=fmaf( t2,a[c].y,a[c].x);   a[c].y=fmaf(-s2,tt,a[c].y);   a[c].x=fmaf( t2,a[c].y,tt);
          tt=fmaf(-t2,a[c1].y,a[c1].x);       a[c1].y=fmaf( s2,tt,a[c1].y); a[c1].x=fmaf(-t2,a[c1].y,tt);
        }
      }
    }
  }
}

// ---------- middle trip: read 64 -> 6 gates -> write 64 -> (1-wave) barrier ----------
template<int TI>
__device__ __forceinline__ void mid_trip(const u32* msk, char* lds,
                                         const float4* __restrict__ gw,
                                         const float4* __restrict__ gwH){
  u32 acc=0;
#pragma unroll
  for(int k=0;k<6;++k) acc ^= TRIPS[TI].lane_c[k]&msk[k];
  const u32 nib = acc>>26;
  u32 base = acc & 0x03FFFFFFu;
  if constexpr (TRIPS[TI].cok){
#pragma unroll
    for(int k=0;k<6;++k){
      const u32 ak=(u32)(__popc(TRIPS[TI].cinv[k]&nib)&1);
      base ^= TRIPS[TI].smb[k]&(0u-ak);
    }
  }
  f2 a[64];
#pragma unroll
  for(int c=0;c<64;++c) a[c]=*(const f2*)(lds+(base^TRIPS[TI].scmb[c]));
  one_gate<TI,0>(a,gw,gwH,nib);
  one_gate<TI,1>(a,gw,gwH,nib);
  one_gate<TI,2>(a,gw,gwH,nib);
  one_gate<TI,3>(a,gw,gwH,nib);
  one_gate<TI,4>(a,gw,gwH,nib);
  one_gate<TI,5>(a,gw,gwH,nib);
#pragma unroll
  for(int c=0;c<64;++c) *(f2*)(lds+(base^TRIPS[TI].scmb[c]))=a[c];
  __syncthreads();   // 1 wave/block: compiles to a cheap waitcnt-only barrier
}

__global__ void prep_kernel(const float* __restrict__ w, float4* __restrict__ gw,
                            float4* __restrict__ gwH){
  const int t = threadIdx.x;
  if(t < NL*NQ){
    const int l=t/NQ, p=t%NQ, q=(NQ-1)-p;
    const float ty=w[(l*NQ+q)*2+0], tz=w[(l*NQ+q)*2+1];
    gw[t]=make_float4(tanf(0.25f*ty), sinf(0.5f*ty), tanf(0.5f*tz), sinf(tz));
    gwH[t]=make_float4(tanf(0.25f*tz), sinf(0.5f*tz), 0.f, 0.f);
  }
}

__global__ __launch_bounds__(BLK) void qsim_kernel(const float* __restrict__ x,
                                                   const float4* __restrict__ gw,
                                                   const float4* __restrict__ gwH,
                                                   float* __restrict__ out)
{
  __shared__ f2 st2[DIM];              // exactly 32768 B -> 5 blocks/CU
  char* lds = (char*)st2;
  const int tid = threadIdx.x;
  const int bb  = blockIdx.x;

  u32 msk[6];
#pragma unroll
  for(int k=0;k<6;++k) msk[k]=0u-((u32)(tid>>k)&1u);

  // ---- trip 0: layer-0 qubits 0-5; masks = bits 0..5 -> 64 consecutive floats ----
  {
    u32 acc=0, raw=0;
#pragma unroll
    for(int k=0;k<6;++k){ acc ^= TRIPS[0].lane_c[k]&msk[k]; raw ^= TRIPS[0].raw6[k]&msk[k]; }
    const u32 base = acc & 0x03FFFFFFu;   // roles structurally 0 at trip 0
    f2 a[64];
    const float* xr = x + (size_t)bb*DIM + raw;
#pragma unroll
    for(int s=0;s<16;++s){
      const float4 v = *reinterpret_cast<const float4*>(xr + 4*s);
      a[4*s+0]=(f2){v.x,0.f}; a[4*s+1]=(f2){v.y,0.f};
      a[4*s+2]=(f2){v.z,0.f}; a[4*s+3]=(f2){v.w,0.f};
    }
    one_gate<0,0>(a,gw,gwH,0u);
    one_gate<0,1>(a,gw,gwH,0u);
    one_gate<0,2>(a,gw,gwH,0u);
    one_gate<0,3>(a,gw,gwH,0u);
    one_gate<0,4>(a,gw,gwH,0u);
    one_gate<0,5>(a,gw,gwH,0u);
#pragma unroll
    for(int c=0;c<64;++c) *(f2*)(lds+(base^TRIPS[0].scmb[c]))=a[c];
    __syncthreads();
  }

  // ---- trips 1..6 ----
  mid_trip<1>(msk,lds,gw,gwH);
  mid_trip<2>(msk,lds,gw,gwH);
  mid_trip<3>(msk,lds,gw,gwH);
  mid_trip<4>(msk,lds,gw,gwH);
  mid_trip<5>(msk,lds,gw,gwH);
  mid_trip<6>(msk,lds,gw,gwH);

  // ---- trip 7 + fused Walsh readout (no write-back) ----
  {
    u32 acc=0, urep=0;
#pragma unroll
    for(int k=0;k<6;++k){ acc ^= TRIPS[7].lane_c[k]&msk[k]; urep ^= TRIPS[7].raw6[k]&msk[k]; }
    const u32 nib = acc>>26;
    u32 base = acc & 0x03FFFFFFu;
    if constexpr (TRIPS[7].cok){
#pragma unroll
      for(int k=0;k<6;++k){
        const u32 ak=(u32)(__popc(TRIPS[7].cinv[k]&nib)&1);
        const u32 mi=0u-ak;
        base ^= TRIPS[7].smb[k]&mi; urep ^= TRIPS[7].rawm[k]&mi;
      }
    }
    f2 a[64];
#pragma unroll
    for(int c=0;c<64;++c) a[c]=*(const f2*)(lds+(base^TRIPS[7].scmb[c]));
    one_gate<7,0>(a,gw,gwH,nib);
    one_gate<7,1>(a,gw,gwH,nib);
    one_gate<7,2>(a,gw,gwH,nib);
    one_gate<7,3>(a,gw,gwH,nib);
    one_gate<7,4>(a,gw,gwH,nib);
    one_gate<7,5>(a,gw,gwH,nib);

    float pr[64];
#pragma unroll
    for(int c=0;c<64;++c) pr[c]=fmaf(a[c].x,a[c].x, a[c].y*a[c].y);
    // Walsh-Hadamard over the 6 combo bits
#pragma unroll
    for(int b=1;b<64;b<<=1){
#pragma unroll
      for(int c=0;c<64;++c){
        if(c&b) continue;
        const float u=pr[c], v=pr[c|b];
        pr[c]=u+v; pr[c|b]=u-v;
      }
    }
    float accq[12];
#pragma unroll
    for(int q=0;q<12;++q){
      const u32 sb = ((u32)__popc(urep & (u32)RDT.pm[q]) & 1u)<<31;
      accq[q]=__uint_as_float(__float_as_uint(pr[RDT.mu[q]])^sb);
    }
    float nrm = pr[0];
#pragma unroll
    for(int o=32;o;o>>=1){
      nrm += __shfl_xor(nrm,o);
#pragma unroll
      for(int q=0;q<12;++q) accq[q]+=__shfl_xor(accq[q],o);
    }
    if(tid==0){
      const float rn = 1.0f/nrm;
#pragma unroll
      for(int q=0;q<12;++q) out[(size_t)bb*NQ+q]=accq[q]*rn;
    }
  }
}

extern "C" void kernel_launch(void* const* d_in, const int* in_sizes, int n_in,
                              void* d_out, int out_size, void* d_ws, size_t ws_size,
                              hipStream_t stream) {
  const float* x = (const float*)d_in[0];
  const float* w = (const float*)d_in[1];
  float* out = (float*)d_out;
  float4* gw  = (float4*)d_ws;
  float4* gwH = gw + NL*NQ;
  const int B = in_sizes[0] / DIM;
  prep_kernel<<<1, 64, 0, stream>>>(w, gw, gwH);
  qsim_kernel<<<B, BLK, 0, stream>>>(x, gw, gwH, out);
}

// Round 15
// 106.175 us; speedup vs baseline: 1.2289x; 1.2289x over previous
//
#include <hip/hip_runtime.h>

#define NQ   12
#define DIM  4096
#define NL   4
#define BLK  256

typedef unsigned short u16;
typedef unsigned int   u32;
typedef float f2 __attribute__((ext_vector_type(2)));

// ---------- compile-time GF(2) linear algebra for the CNOT-chain permutation ----------
struct L12 { u16 b[NQ]; };

static constexpr u32 lap(const L12& A, u32 x){ u32 r=0; for(int p=0;p<NQ;++p) if((x>>p)&1u) r^=A.b[p]; return r; }
static constexpr L12 lcomp(const L12& A, const L12& B){ L12 r{}; for(int p=0;p<NQ;++p) r.b[p]=(u16)lap(A,(u32)B.b[p]); return r; }
static constexpr L12 lident(){ L12 r{}; for(int p=0;p<NQ;++p) r.b[p]=(u16)(1u<<p); return r; }

static constexpr u32 applyT(u32 i){
  i ^= ((i>>0)&1u) << 11;                            // CNOT(11,0): bit11 ^= bit0
  for(int q=10;q>=0;--q){ int pc=11-q, pt=10-q; i ^= ((i>>pc)&1u) << pt; }
  return i;
}
static constexpr L12 lT(){ L12 t{}; for(int p=0;p<NQ;++p) t.b[p]=(u16)applyT(1u<<p); return t; }

static constexpr L12 linv(const L12& A){              // GF(2) Gauss-Jordan
  u16 v[NQ]={}; u16 u[NQ]={};
  for(int p=0;p<NQ;++p){ v[p]=A.b[p]; u[p]=(u16)(1u<<p); }
  for(int t=0;t<NQ;++t){
    int p=t; while(!((v[p]>>t)&1u)) ++p;
    u16 tv=v[p]; v[p]=v[t]; v[t]=tv; u16 tu=u[p]; u[p]=u[t]; u[t]=tu;
    for(int k=0;k<NQ;++k) if(k!=t && ((v[k]>>t)&1u)){ v[k]^=v[t]; u[k]^=u[t]; }
  }
  L12 r{}; for(int p=0;p<NQ;++p) r.b[p]=u[p]; return r;
}
static constexpr L12 ltr(const L12& A){
  L12 r{}; for(int p=0;p<NQ;++p) for(int q=0;q<NQ;++q) if((A.b[p]>>q)&1u) r.b[q]=(u16)(r.b[q]|(1u<<p));
  return r;
}
static constexpr int cpop(u32 v){ int n=0; while(v){ n+=(int)(v&1u); v>>=1; } return n; }

struct Tables {
  u16 cm[12][16];   // [step][combo] xor-offsets spanning the 4 gate masks
  u16 wg[12][4];    // [step][gate] parity mask: a0/a1 role selector
  u16 sp[12][4];    // [step] sorted pivot bit positions
  u16 wexp[NQ];     // final <Z> parity masks: rows of (T^4)^{-T}
};

static constexpr Tables make_tables(){
  Tables tb{};
  const L12 T   = lT();
  const L12 Tit = ltr(linv(T));   // T^{-T}
  L12 A = lident();               // A_l = T^l   (stored_index = A_l(true_index))
  L12 W = lident();               // W_l = A_l^{-T}
  for(int l=0;l<NL;++l){
    for(int g=0;g<3;++g){
      const int st = l*3+g;
      u16 mm[4]={0,0,0,0};
      for(int i=0;i<4;++i){ mm[i]=A.b[4*g+i]; tb.wg[st][i]=W.b[4*g+i]; }
      u32 ech[4]={0,0,0,0}; int piv[4]={0,0,0,0};
      for(int i=0;i<4;++i){
        u32 v=mm[i];
        for(int k=0;k<i;++k) if((v>>piv[k])&1u) v^=ech[k];
        int t2=11; while(!((v>>t2)&1u)) --t2;
        piv[i]=t2; ech[i]=v;
      }
      for(int a2=0;a2<4;++a2) for(int b2=a2+1;b2<4;++b2)
        if(piv[b2]<piv[a2]){ int tt=piv[a2]; piv[a2]=piv[b2]; piv[b2]=tt; }
      for(int i=0;i<4;++i) tb.sp[st][i]=(u16)piv[i];
      for(int c=0;c<16;++c){ u32 m=0; for(int i=0;i<4;++i) if((c>>i)&1) m^=mm[i]; tb.cm[st][c]=(u16)m; }
    }
    A = lcomp(A, T);
    W = lcomp(W, Tit);
  }
  for(int p=0;p<NQ;++p) tb.wexp[p]=W.b[p];
  return tb;
}

__device__ constexpr Tables TB = make_tables();

// ---------- LDS swizzle: slot = j ^ fold(j>>4), fold linear over GF(2) ----------
static constexpr u16 UIMG[12] = {1,2,4,8, 3,5,6,7, 9,10,11,13};

static constexpr u32 swz(u32 j){
  u32 f=0;
  for(int k=4;k<12;++k) if((j>>k)&1u) f ^= (u32)UIMG[k];
  return j ^ (f & 15u);
}

struct Derived {
  u32 lane_c[12][8];  // tid bit k -> (swz(1<<pos)<<3) | (role-parity nibble <<28)
  u32 smb[12][4];     // swz(cm[1<<i])<<3  (rep parity correction, swizzled)
  u32 scmb[12][16];   // swz(cm[c])<<3     (coset member byte offsets)
  u32 g0lane[8];      // step 0: unswizzled element-index contribution of tid bit k
  u32 u11lane[8];     // step 11: unswizzled index contribution of tid bit k
  u32 u11smb[4];      // step 11: unswizzled cm[1<<i]
  u16 pm[12];         // wexp[11-q]: per-thread parity mask on unswizzled rep
  u16 mu[12];         // Walsh index per output q
};

static constexpr Derived make_derived(){
  const Tables tb = make_tables();
  Derived d{};
  for(int st=0; st<12; ++st){
    bool isp[12]={false,false,false,false,false,false,false,false,false,false,false,false};
    for(int i=0;i<4;++i) isp[tb.sp[st][i]]=true;
    int np[8]={}; int nn=0;
    for(int p=0;p<12;++p) if(!isp[p]) np[nn++]=p;
    // choose 6 of 8 non-pivot positions for lane bits s.t. their GF(2)^4
    // bank-pair images have rank 4 -> exactly 4 lanes/bank-pair (b64 floor)
    int best=-1;
    for(int ms=0; ms<256; ++ms){
      int pc=0; for(int k=0;k<8;++k) pc+=(ms>>k)&1;
      if(pc!=6) continue;
      u16 bas[4]={0,0,0,0}; int r=0;
      for(int k=0;k<8;++k){
        if(!((ms>>k)&1)) continue;
        u16 x=(u16)(UIMG[np[k]]&15);
        while(x){
          int hb=3; while(!((x>>hb)&1)) --hb;
          if(bas[hb]) x=(u16)(x^bas[hb]);
          else { bas[hb]=x; ++r; x=0; }
        }
      }
      if(r==4){ best=ms; break; }
    }
    if(best<0) best=0x3F;
    int pos[8]={}; int lo=0, hi=6;
    for(int k=0;k<8;++k){ if((best>>k)&1) pos[lo++]=np[k]; else pos[hi++]=np[k]; }
    for(int k=0;k<8;++k){
      const u32 addr = swz(1u<<pos[k])<<3;
      u32 nib=0;
      for(int i=0;i<4;++i) nib |= (u32)((tb.wg[st][i]>>pos[k])&1u)<<i;
      d.lane_c[st][k] = addr | (nib<<28);
      if(st==0)  d.g0lane[k]  = 1u<<pos[k];
      if(st==11) d.u11lane[k] = 1u<<pos[k];
    }
    for(int i=0;i<4;++i)  d.smb[st][i]  = swz((u32)tb.cm[st][1<<i])<<3;
    for(int c=0;c<16;++c) d.scmb[st][c] = swz((u32)tb.cm[st][c])<<3;
    if(st==11) for(int i=0;i<4;++i) d.u11smb[i] = (u32)tb.cm[11][1<<i];
  }
  for(int q=0;q<12;++q){
    d.pm[q] = tb.wexp[11-q];
    u32 m=0;
    for(int i=0;i<4;++i) m |= (u32)(cpop((u32)tb.cm[11][1u<<i] & (u32)tb.wexp[11-q])&1)<<i;
    d.mu[q]=(u16)m;
  }
  return d;
}

__device__ constexpr Derived DV = make_derived();

// ---------- 4 commuting gates via 3-shear rotations (all-FMA) ----------
// gw[g] = {tan(ty/4), sin(ty/2), tan(tz/2), sin(tz)}  (global phase dropped)
template<int ST, bool WITHW>
__device__ __forceinline__ void gates(f2 (&a)[16], const float4* __restrict__ gw){
#pragma unroll
  for(int i=0;i<4;++i){
    const float4 g = gw[ST*4+i];
    const f2 mt = {-g.x, -g.x};
    const f2 sy = { g.y,  g.y};
#pragma unroll
    for(int c=0;c<16;++c){
      if((c>>i)&1) continue;
      const int c1 = c|(1<<i);
      f2 u = __builtin_elementwise_fma(mt, a[c1], a[c]);   // u  = a0 - t*a1
      f2 v = __builtin_elementwise_fma(sy, u, a[c1]);      // a1'= a1 + s*u
      a[c] = __builtin_elementwise_fma(mt, v, u);          // a0'= u  - t*a1'
      if(WITHW){                                           // rotate (v.x,v.y) by +tz
        const float t = fmaf(-g.z, v.y, v.x);
        v.y = fmaf( g.w, t, v.y);
        v.x = fmaf(-g.z, v.y, t);
      }
      a[c1]=v;
    }
  }
}

template<int ST, bool WITHW>
__device__ __forceinline__ void mid_step(const u32* msk, char* lds, const float4* __restrict__ gw){
  u32 acc=0;
#pragma unroll
  for(int k=0;k<8;++k) acc ^= DV.lane_c[ST][k]&msk[k];
  const u32 nib = acc>>28;
  u32 base = acc & 0x0FFFFFFFu;
#pragma unroll
  for(int i=0;i<4;++i) base ^= DV.smb[ST][i] & (0u-((nib>>i)&1u));
  u32 ad[16]; f2 a[16];
#pragma unroll
  for(int c=0;c<16;++c){
    ad[c] = base ^ DV.scmb[ST][c];
    a[c] = *(const f2*)(lds+ad[c]);
  }
  gates<ST,WITHW>(a,gw);
#pragma unroll
  for(int c=0;c<16;++c){ *(f2*)(lds+ad[c]) = a[c]; }
  __syncthreads();
}

__global__ void prep_kernel(const float* __restrict__ w, float4* __restrict__ gw){
  const int t = threadIdx.x;
  if(t < NL*NQ){
    const int l=t/NQ, p=t%NQ, q=(NQ-1)-p;
    const float ty=w[(l*NQ+q)*2+0], tz=w[(l*NQ+q)*2+1];
    gw[t]=make_float4(tanf(0.25f*ty), sinf(0.5f*ty), tanf(0.5f*tz), sinf(tz));
  }
}

__global__ __launch_bounds__(BLK, 5) void qsim_kernel(const float* __restrict__ x,
                                                      const float4* __restrict__ gw,
                                                      float* __restrict__ out)
{
  __shared__ f2 st2[DIM];              // exactly 32768 B
  char* lds = (char*)st2;
  const int tid = threadIdx.x;
  const int bb  = blockIdx.x;

  u32 msk[8];
#pragma unroll
  for(int k=0;k<8;++k) msk[k]=0u-((u32)(tid>>k)&1u);

  // ---- step 0: masks are bits 0..3 -> coset = 16 consecutive floats in global ----
  u32 rep0=0, acc0=0;
#pragma unroll
  for(int k=0;k<8;++k){ rep0 ^= DV.g0lane[k]&msk[k]; acc0 ^= DV.lane_c[0][k]&msk[k]; }
  const u32 base0 = acc0 & 0x0FFFFFFFu;   // nib == 0 at step 0

  f2 a[16];
  const float* xr = x + (size_t)bb*DIM + rep0;
#pragma unroll
  for(int s=0;s<4;++s){
    const float4 v = *reinterpret_cast<const float4*>(xr + 4*s);
    a[4*s+0]=(f2){v.x,0.f}; a[4*s+1]=(f2){v.y,0.f};
    a[4*s+2]=(f2){v.z,0.f}; a[4*s+3]=(f2){v.w,0.f};
  }
  gates<0,true>(a,gw);
#pragma unroll
  for(int c=0;c<16;++c){ *(f2*)(lds + (base0 ^ DV.scmb[0][c])) = a[c]; }
  __syncthreads();

  // ---- steps 1..10: LDS round trips ----
  mid_step<1,true >(msk,lds,gw);
  mid_step<2,true >(msk,lds,gw);
  mid_step<3,true >(msk,lds,gw);
  mid_step<4,true >(msk,lds,gw);
  mid_step<5,true >(msk,lds,gw);
  mid_step<6,true >(msk,lds,gw);
  mid_step<7,true >(msk,lds,gw);
  mid_step<8,true >(msk,lds,gw);
  mid_step<9,false>(msk,lds,gw);     // last layer: RZ phase dropped (|amp|^2 readout)
  mid_step<10,false>(msk,lds,gw);

  // ---- step 11 + fused Walsh readout (no write-back) ----
  {
    u32 acc=0, urep=0;
#pragma unroll
    for(int k=0;k<8;++k){ acc ^= DV.lane_c[11][k]&msk[k]; urep ^= DV.u11lane[k]&msk[k]; }
    const u32 nib = acc>>28;
    u32 base = acc & 0x0FFFFFFFu;
#pragma unroll
    for(int i=0;i<4;++i){ const u32 mi=0u-((nib>>i)&1u); base ^= DV.smb[11][i]&mi; urep ^= DV.u11smb[i]&mi; }
#pragma unroll
    for(int c=0;c<16;++c){
      a[c] = *(const f2*)(lds + (base ^ DV.scmb[11][c]));
    }
    gates<11,false>(a,gw);

    float pr[16];
#pragma unroll
    for(int c=0;c<16;++c) pr[c]=fmaf(a[c].x,a[c].x, a[c].y*a[c].y);
    // Walsh-Hadamard over the 4 combo bits: W[m] = sum_c (-1)^{popc(c&m)} pr[c]
#pragma unroll
    for(int b=1;b<16;b<<=1){
#pragma unroll
      for(int c=0;c<16;++c){
        if(c&b) continue;
        const float u=pr[c], v=pr[c|b];
        pr[c]=u+v; pr[c|b]=u-v;
      }
    }
    float accq[12];
#pragma unroll
    for(int q=0;q<12;++q){
      const u32 sb = ((u32)__popc(urep & (u32)DV.pm[q]) & 1u)<<31;
      accq[q]=__uint_as_float(__float_as_uint(pr[DV.mu[q]])^sb);
    }
    float nrm2 = pr[0];
#pragma unroll
    for(int o=32;o;o>>=1){
      nrm2 += __shfl_xor(nrm2,o);
#pragma unroll
      for(int q=0;q<12;++q) accq[q]+=__shfl_xor(accq[q],o);
    }
    __syncthreads();                      // all waves done reading step 11
    float* wredf = (float*)lds;           // alias reduction buffer into state LDS
    const int wid=tid>>6;
    if((tid&63)==0){
#pragma unroll
      for(int q=0;q<12;++q) wredf[wid*13+q]=accq[q];
      wredf[wid*13+12]=nrm2;
    }
    __syncthreads();
    if(tid<NQ){
      const float s0=wredf[0*13+tid]+wredf[1*13+tid]+wredf[2*13+tid]+wredf[3*13+tid];
      const float sn=wredf[0*13+12]+wredf[1*13+12]+wredf[2*13+12]+wredf[3*13+12];
      out[(size_t)bb*NQ+tid]=s0/sn;
    }
  }
}

extern "C" void kernel_launch(void* const* d_in, const int* in_sizes, int n_in,
                              void* d_out, int out_size, void* d_ws, size_t ws_size,
                              hipStream_t stream) {
  const float* x = (const float*)d_in[0];
  const float* w = (const float*)d_in[1];
  float* out = (float*)d_out;
  float4* gw = (float4*)d_ws;
  const int B = in_sizes[0] / DIM;
  prep_kernel<<<1, 64, 0, stream>>>(w, gw);
  qsim_kernel<<<B, BLK, 0, stream>>>(x, gw, out);
}